// Round 1
// baseline (4497.912 us; speedup 1.0000x reference)
//
#include <hip/hip_runtime.h>
#include <hip/hip_bf16.h>
#include <stdint.h>

#define B_ 2
#define S_ 2048
#define E_ 1024
#define H_ 16
#define D_ 64
#define M_ (B_*S_)      // 4096
#define N3 (3*E_)       // 3072

typedef unsigned short u16;
typedef float f32x4 __attribute__((ext_vector_type(4)));
typedef __bf16 bf16x8 __attribute__((ext_vector_type(8)));

__device__ __forceinline__ u16 f2bf(float f){
    uint32_t u = __float_as_uint(f);
    u += 0x7fffu + ((u >> 16) & 1u);
    return (u16)(u >> 16);
}
__device__ __forceinline__ float blo(uint32_t u){ return __uint_as_float(u << 16); }
__device__ __forceinline__ float bhi(uint32_t u){ return __uint_as_float(u & 0xffff0000u); }

// ---------------- elementwise cast f32 -> bf16 (vectorized) ----------------
__global__ __launch_bounds__(256) void cast_f32_bf16(const float* __restrict__ in,
                                                     u16* __restrict__ out, int n4){
    int i = blockIdx.x * 256 + threadIdx.x;
    if (i < n4){
        float4 v = ((const float4*)in)[i];
        uint2 p;
        p.x = (uint32_t)f2bf(v.x) | ((uint32_t)f2bf(v.y) << 16);
        p.y = (uint32_t)f2bf(v.z) | ((uint32_t)f2bf(v.w) << 16);
        ((uint2*)out)[i] = p;
    }
}

// ---------------- tiled transpose + cast: in[R][C] f32 -> out[C][R] bf16 ----------------
__global__ __launch_bounds__(256) void transpose_cast(const float* __restrict__ in,
                                                      u16* __restrict__ out, int R, int C){
    __shared__ float t[32][33];
    int bx = blockIdx.x, by = blockIdx.y;
    int tx = threadIdx.x, ty = threadIdx.y;
    int x = bx * 32 + tx;
    #pragma unroll
    for (int i = 0; i < 4; i++)
        t[ty + 8*i][tx] = in[(size_t)(by*32 + ty + 8*i) * C + x];
    __syncthreads();
    #pragma unroll
    for (int i = 0; i < 4; i++)
        out[(size_t)(bx*32 + ty + 8*i) * R + by*32 + tx] = f2bf(t[tx][ty + 8*i]);
}

// ---------------- bf16 MFMA GEMM: C[M][N] = A[M][K] * BT[N][K]^T + bias ----------------
// 128x128 tile, BK=64, 4 waves (2x2), each wave 64x64 = 4x4 mfma tiles of 16x16x32.
template<bool OUT_BF16>
__global__ __launch_bounds__(256) void gemm_bf16(const u16* __restrict__ A,
                                                 const u16* __restrict__ BT,
                                                 const float* __restrict__ bias,
                                                 void* __restrict__ Cout,
                                                 int M, int N, int K){
    __shared__ u16 Al[128 * 64];
    __shared__ u16 Bl[128 * 64];
    int nb = N >> 7;
    int bm = blockIdx.x / nb, bn = blockIdx.x % nb;
    int row0 = bm << 7, col0 = bn << 7;
    int tid  = threadIdx.x;
    int wave = tid >> 6, lane = tid & 63;
    int wm = wave >> 1, wn = wave & 1;
    int lr = lane & 15, lk = (lane >> 4) << 3;
    int trow = tid >> 3, tcol = (tid & 7) << 3;

    f32x4 acc[4][4] = {};

    for (int k0 = 0; k0 < K; k0 += 64){
        // stage A and BT tiles: 128x64 bf16 each, global_load_lds 16B/lane
        #pragma unroll
        for (int i = 0; i < 4; i++){
            const u16* ga = A + (size_t)(row0 + i*32 + trow) * K + k0 + tcol;
            __builtin_amdgcn_global_load_lds(
                (const __attribute__((address_space(1))) void*)ga,
                (__attribute__((address_space(3))) void*)&Al[i*2048 + wave*512],
                16, 0, 0);
        }
        #pragma unroll
        for (int i = 0; i < 4; i++){
            const u16* gb = BT + (size_t)(col0 + i*32 + trow) * K + k0 + tcol;
            __builtin_amdgcn_global_load_lds(
                (const __attribute__((address_space(1))) void*)gb,
                (__attribute__((address_space(3))) void*)&Bl[i*2048 + wave*512],
                16, 0, 0);
        }
        __syncthreads();

        #pragma unroll
        for (int ks = 0; ks < 2; ks++){
            bf16x8 af[4], bfr[4];
            #pragma unroll
            for (int m = 0; m < 4; m++)
                af[m] = *(const bf16x8*)&Al[(wm*64 + m*16 + lr) * 64 + ks*32 + lk];
            #pragma unroll
            for (int n = 0; n < 4; n++)
                bfr[n] = *(const bf16x8*)&Bl[(wn*64 + n*16 + lr) * 64 + ks*32 + lk];
            #pragma unroll
            for (int m = 0; m < 4; m++)
                #pragma unroll
                for (int n = 0; n < 4; n++)
                    acc[m][n] = __builtin_amdgcn_mfma_f32_16x16x32_bf16(af[m], bfr[n], acc[m][n], 0, 0, 0);
        }
        __syncthreads();
    }

    // epilogue: C/D layout col = lane&15, row = (lane>>4)*4 + j  [measured m89/m91]
    #pragma unroll
    for (int m = 0; m < 4; m++){
        int gr = row0 + wm*64 + m*16 + ((lane >> 4) << 2);
        #pragma unroll
        for (int n = 0; n < 4; n++){
            int gc = col0 + wn*64 + n*16 + lr;
            float bv = bias[gc];
            #pragma unroll
            for (int j = 0; j < 4; j++){
                float v = acc[m][n][j] + bv;
                if (OUT_BF16) ((u16*)Cout)[(size_t)(gr + j) * N + gc] = f2bf(v);
                else          ((float*)Cout)[(size_t)(gr + j) * N + gc] = v;
            }
        }
    }
}

// ---------------- causal flash attention, fp32, one thread per query row ----------------
// qkv: [B*S][3E] bf16 (q | k | v per row). ctx out: [B*S][E] bf16 (merged heads).
__global__ __launch_bounds__(256) void attn_causal(const u16* __restrict__ qkv,
                                                   u16* __restrict__ ctx){
    int bid = blockIdx.x;
    int sb = bid & 7;            // S/256 = 8 blocks per (b,h)
    int h  = (bid >> 3) & 15;
    int b  = bid >> 7;
    int s  = sb * 256 + threadIdx.x;

    const u16* base = qkv + (size_t)b * S_ * N3;
    const uint32_t* qr = (const uint32_t*)(base + (size_t)s * N3 + h * 64);

    float q[64];
    #pragma unroll
    for (int i = 0; i < 32; i++){
        uint32_t u = qr[i];
        q[2*i]   = blo(u) * 0.125f;   // 1/sqrt(64)
        q[2*i+1] = bhi(u) * 0.125f;
    }
    float o[64];
    #pragma unroll
    for (int i = 0; i < 64; i++) o[i] = 0.f;
    float mx = -3.0e38f, l = 0.f;

    int jend = sb * 256 + 256;   // causal bound for this block (uniform)
    for (int j0 = 0; j0 < jend; j0 += 16){
        float sc[16];
        #pragma unroll
        for (int jj = 0; jj < 16; jj++){
            int j = j0 + jj;
            const uint32_t* kr = (const uint32_t*)(base + (size_t)j * N3 + E_ + h * 64);
            float sv = 0.f;
            #pragma unroll
            for (int i = 0; i < 32; i++){
                uint32_t u = kr[i];                  // uniform address -> scalar load
                sv = fmaf(q[2*i],   blo(u), sv);
                sv = fmaf(q[2*i+1], bhi(u), sv);
            }
            sc[jj] = (j <= s) ? sv : -3.0e38f;       // causal mask
        }
        float tmax = sc[0];
        #pragma unroll
        for (int jj = 1; jj < 16; jj++) tmax = fmaxf(tmax, sc[jj]);
        float mn  = fmaxf(mx, tmax);
        float fac = __expf(mx - mn);
        mx = mn;
        l *= fac;
        #pragma unroll
        for (int i = 0; i < 64; i++) o[i] *= fac;
        #pragma unroll
        for (int jj = 0; jj < 16; jj++){
            int j = j0 + jj;
            float p = __expf(sc[jj] - mn);           // masked -> exp(-huge) = 0
            l += p;
            const uint32_t* vr = (const uint32_t*)(base + (size_t)j * N3 + 2*E_ + h * 64);
            #pragma unroll
            for (int i = 0; i < 32; i++){
                uint32_t u = vr[i];
                o[2*i]   = fmaf(p, blo(u), o[2*i]);
                o[2*i+1] = fmaf(p, bhi(u), o[2*i+1]);
            }
        }
    }
    float inv = 1.f / l;
    u16* orow = ctx + (size_t)(b * S_ + s) * E_ + h * 64;
    #pragma unroll
    for (int i = 0; i < 32; i++){
        uint32_t pck = (uint32_t)f2bf(o[2*i] * inv) | ((uint32_t)f2bf(o[2*i+1] * inv) << 16);
        ((uint32_t*)orow)[i] = pck;
    }
}

// ---------------- launch ----------------
extern "C" void kernel_launch(void* const* d_in, const int* in_sizes, int n_in,
                              void* d_out, int out_size, void* d_ws, size_t ws_size,
                              hipStream_t stream){
    const float* x      = (const float*)d_in[0];
    const float* w_attn = (const float*)d_in[1];
    const float* b_attn = (const float*)d_in[2];
    const float* w_proj = (const float*)d_in[3];
    const float* b_proj = (const float*)d_in[4];
    float* out = (float*)d_out;

    char* ws = (char*)d_ws;
    u16* xb   = (u16*)(ws);                         //  8 MB  [4096][1024] bf16
    u16* waT  = (u16*)(ws + 8u*1024*1024);          //  6 MB  [3072][1024] bf16
    u16* wpT  = (u16*)(ws + 14u*1024*1024);         //  2 MB  [1024][1024] bf16
    u16* qkv  = (u16*)(ws + 16u*1024*1024);         // 24 MB  [4096][3072] bf16
    u16* ctxb = (u16*)(ws + 40u*1024*1024);         //  8 MB  [4096][1024] bf16

    // 1) cast x -> bf16
    cast_f32_bf16<<<(M_*E_/4 + 255)/256, 256, 0, stream>>>(x, xb, M_*E_/4);
    // 2) transpose+cast weights to [N][K] bf16
    transpose_cast<<<dim3(N3/32, E_/32), dim3(32, 8), 0, stream>>>(w_attn, waT, E_, N3);
    transpose_cast<<<dim3(E_/32, E_/32), dim3(32, 8), 0, stream>>>(w_proj, wpT, E_, E_);
    // 3) QKV projection (bf16 out, bias added)
    gemm_bf16<true><<<(M_/128)*(N3/128), 256, 0, stream>>>(xb, waT, b_attn, qkv, M_, N3, E_);
    // 4) causal flash attention -> merged ctx bf16
    attn_causal<<<B_*H_*(S_/256), 256, 0, stream>>>(qkv, ctxb);
    // 5) output projection (fp32 out)
    gemm_bf16<false><<<(M_/128)*(E_/128), 256, 0, stream>>>(ctxb, wpT, b_proj, out, M_, E_, E_);
}

// Round 2
// 214.155 us; speedup vs baseline: 21.0031x; 21.0031x over previous
//
#include <hip/hip_runtime.h>
#include <hip/hip_bf16.h>
#include <stdint.h>

#define B_ 2
#define S_ 2048
#define E_ 1024
#define H_ 16
#define D_ 64
#define M_ (B_*S_)      // 4096
#define N3 (3*E_)       // 3072

typedef unsigned short u16;
typedef float f32x4 __attribute__((ext_vector_type(4)));
typedef __bf16 bf16x8 __attribute__((ext_vector_type(8)));
typedef u16 u16x8 __attribute__((ext_vector_type(8)));

__device__ __forceinline__ u16 f2bf(float f){
    uint32_t u = __float_as_uint(f);
    u += 0x7fffu + ((u >> 16) & 1u);
    return (u16)(u >> 16);
}
__device__ __forceinline__ float blo(uint32_t u){ return __uint_as_float(u << 16); }
__device__ __forceinline__ float bhi(uint32_t u){ return __uint_as_float(u & 0xffff0000u); }

__device__ __forceinline__ float rmax16(float v){
    v = fmaxf(v, __shfl_xor(v, 1));
    v = fmaxf(v, __shfl_xor(v, 2));
    v = fmaxf(v, __shfl_xor(v, 4));
    v = fmaxf(v, __shfl_xor(v, 8));
    return v;
}
__device__ __forceinline__ float rsum16(float v){
    v += __shfl_xor(v, 1);
    v += __shfl_xor(v, 2);
    v += __shfl_xor(v, 4);
    v += __shfl_xor(v, 8);
    return v;
}

// ---------------- elementwise cast f32 -> bf16 (vectorized) ----------------
__global__ __launch_bounds__(256) void cast_f32_bf16(const float* __restrict__ in,
                                                     u16* __restrict__ out, int n4){
    int i = blockIdx.x * 256 + threadIdx.x;
    if (i < n4){
        float4 v = ((const float4*)in)[i];
        uint2 p;
        p.x = (uint32_t)f2bf(v.x) | ((uint32_t)f2bf(v.y) << 16);
        p.y = (uint32_t)f2bf(v.z) | ((uint32_t)f2bf(v.w) << 16);
        ((uint2*)out)[i] = p;
    }
}

// ---------------- tiled transpose + cast: in[R][C] f32 -> out[C][R] bf16 ----------------
__global__ __launch_bounds__(256) void transpose_cast(const float* __restrict__ in,
                                                      u16* __restrict__ out, int R, int C){
    __shared__ float t[32][33];
    int bx = blockIdx.x, by = blockIdx.y;
    int tx = threadIdx.x, ty = threadIdx.y;
    int x = bx * 32 + tx;
    #pragma unroll
    for (int i = 0; i < 4; i++)
        t[ty + 8*i][tx] = in[(size_t)(by*32 + ty + 8*i) * C + x];
    __syncthreads();
    #pragma unroll
    for (int i = 0; i < 4; i++)
        out[(size_t)(bx*32 + ty + 8*i) * R + by*32 + tx] = f2bf(t[tx][ty + 8*i]);
}

// ---------------- bf16 MFMA GEMM: C[M][N] = A[M][K] * BT[N][K]^T + bias ----------------
template<bool OUT_BF16>
__global__ __launch_bounds__(256) void gemm_bf16(const u16* __restrict__ A,
                                                 const u16* __restrict__ BT,
                                                 const float* __restrict__ bias,
                                                 void* __restrict__ Cout,
                                                 int M, int N, int K){
    __shared__ u16 Al[128 * 64];
    __shared__ u16 Bl[128 * 64];
    int nb = N >> 7;
    int bm = blockIdx.x / nb, bn = blockIdx.x % nb;
    int row0 = bm << 7, col0 = bn << 7;
    int tid  = threadIdx.x;
    int wave = tid >> 6, lane = tid & 63;
    int wm = wave >> 1, wn = wave & 1;
    int lr = lane & 15, lk = (lane >> 4) << 3;
    int trow = tid >> 3, tcol = (tid & 7) << 3;

    f32x4 acc[4][4] = {};

    for (int k0 = 0; k0 < K; k0 += 64){
        #pragma unroll
        for (int i = 0; i < 4; i++){
            const u16* ga = A + (size_t)(row0 + i*32 + trow) * K + k0 + tcol;
            __builtin_amdgcn_global_load_lds(
                (const __attribute__((address_space(1))) void*)ga,
                (__attribute__((address_space(3))) void*)&Al[i*2048 + wave*512],
                16, 0, 0);
        }
        #pragma unroll
        for (int i = 0; i < 4; i++){
            const u16* gb = BT + (size_t)(col0 + i*32 + trow) * K + k0 + tcol;
            __builtin_amdgcn_global_load_lds(
                (const __attribute__((address_space(1))) void*)gb,
                (__attribute__((address_space(3))) void*)&Bl[i*2048 + wave*512],
                16, 0, 0);
        }
        __syncthreads();

        #pragma unroll
        for (int ks = 0; ks < 2; ks++){
            bf16x8 af[4], bfr[4];
            #pragma unroll
            for (int m = 0; m < 4; m++)
                af[m] = *(const bf16x8*)&Al[(wm*64 + m*16 + lr) * 64 + ks*32 + lk];
            #pragma unroll
            for (int n = 0; n < 4; n++)
                bfr[n] = *(const bf16x8*)&Bl[(wn*64 + n*16 + lr) * 64 + ks*32 + lk];
            #pragma unroll
            for (int m = 0; m < 4; m++)
                #pragma unroll
                for (int n = 0; n < 4; n++)
                    acc[m][n] = __builtin_amdgcn_mfma_f32_16x16x32_bf16(af[m], bfr[n], acc[m][n], 0, 0, 0);
        }
        __syncthreads();
    }

    #pragma unroll
    for (int m = 0; m < 4; m++){
        int gr = row0 + wm*64 + m*16 + ((lane >> 4) << 2);
        #pragma unroll
        for (int n = 0; n < 4; n++){
            int gc = col0 + wn*64 + n*16 + lr;
            float bv = bias[gc];
            #pragma unroll
            for (int j = 0; j < 4; j++){
                float v = acc[m][n][j] + bv;
                if (OUT_BF16) ((u16*)Cout)[(size_t)(gr + j) * N + gc] = f2bf(v);
                else          ((float*)Cout)[(size_t)(gr + j) * N + gc] = v;
            }
        }
    }
}

// ---------------- MFMA causal flash attention ----------------
// qkv: [B*S][3E] bf16 (q|k|v). ctx: [B*S][E] bf16 merged heads.
// Block = (b, h, 128-query tile); 4 waves x 32 q-rows. KV tile = 64 rows.
__global__ __launch_bounds__(256) void attn_mfma(const u16* __restrict__ qkv,
                                                 u16* __restrict__ ctx){
    __shared__ u16 Kl[64 * 64];      // K rows, XOR-swizzled 16B chunks
    __shared__ u16 Vt[64 * 72];      // V transposed [d][k], row pad 72
    __shared__ u16 Pl[4][32 * 72];   // per-wave P tile [q][k], row pad 72

    int t  = blockIdx.x;
    int raw = t & 15;
    int qb = (raw & 1) ? (15 - (raw >> 1)) : (raw >> 1);  // balance causal work
    int h  = (t >> 4) & 15;
    int b  = t >> 8;
    int q0 = qb * 128;

    int tid  = threadIdx.x;
    int wq   = tid >> 6, lane = tid & 63;
    int g    = lane >> 4, lr = lane & 15;

    const u16* base = qkv + (size_t)b * S_ * N3;

    // Q fragments (A-layout: row=lr, k-slice=(g*8)), pre-scaled by 1/sqrt(64)
    bf16x8 qf[2][2];
    #pragma unroll
    for (int m = 0; m < 2; m++){
        #pragma unroll
        for (int kk = 0; kk < 2; kk++){
            u16x8 v = *(const u16x8*)(base + (size_t)(q0 + wq*32 + m*16 + lr) * N3 + h*64 + kk*32 + g*8);
            u16x8 r;
            #pragma unroll
            for (int i = 0; i < 8; i++)
                r[i] = f2bf(__uint_as_float((uint32_t)v[i] << 16) * 0.125f);
            qf[m][kk] = __builtin_bit_cast(bf16x8, r);
        }
    }

    f32x4 oacc[2][4] = {};
    float mrun[2][4], lrun[2][4];
    #pragma unroll
    for (int m = 0; m < 2; m++)
        #pragma unroll
        for (int j = 0; j < 4; j++){ mrun[m][j] = -1e30f; lrun[m][j] = 0.f; }

    int qmin = q0 + wq*32, qmax = qmin + 31;
    int nkt  = q0/64 + 2;

    for (int kt = 0; kt < nkt; kt++){
        int k0 = kt * 64;

        // ---- stage K tile (64x64), swizzled: byte = row*128 + (chunk*16 ^ ((row&7)<<4)) ----
        #pragma unroll
        for (int c = 0; c < 2; c++){
            int idx = c*256 + tid;
            int row = idx >> 3, ch = idx & 7;
            uint4 v = *(const uint4*)(base + (size_t)(k0 + row) * N3 + E_ + h*64 + ch*8);
            *(uint4*)((char*)Kl + row*128 + ((ch*16) ^ ((row & 7) << 4))) = v;
        }
        // ---- stage V transposed: Vt[d][k], pack 2 k per dword ----
        {
            int rp = tid >> 3, ch = tid & 7;          // rowpair 0..31, 16B chunk 0..7
            u16x8 a  = *(const u16x8*)(base + (size_t)(k0 + 2*rp)     * N3 + 2*E_ + h*64 + ch*8);
            u16x8 bv = *(const u16x8*)(base + (size_t)(k0 + 2*rp + 1) * N3 + 2*E_ + h*64 + ch*8);
            #pragma unroll
            for (int e = 0; e < 8; e++){
                uint32_t pk = (uint32_t)a[e] | ((uint32_t)bv[e] << 16);
                *(uint32_t*)((char*)Vt + ((size_t)(ch*8 + e)*72 + 2*rp)*2) = pk;
            }
        }
        __syncthreads();

        if (k0 <= qmax){
            // ---- QK^T: S[32q][64k] per wave ----
            f32x4 sac[2][4] = {};
            bf16x8 kf[4][2];
            #pragma unroll
            for (int n = 0; n < 4; n++){
                #pragma unroll
                for (int kk = 0; kk < 2; kk++){
                    int row = n*16 + lr;
                    kf[n][kk] = *(const bf16x8*)((char*)Kl + row*128 + ((kk*64 + g*16) ^ ((row & 7) << 4)));
                }
            }
            #pragma unroll
            for (int m = 0; m < 2; m++)
                #pragma unroll
                for (int n = 0; n < 4; n++){
                    sac[m][n] = __builtin_amdgcn_mfma_f32_16x16x32_bf16(qf[m][0], kf[n][0], sac[m][n], 0, 0, 0);
                    sac[m][n] = __builtin_amdgcn_mfma_f32_16x16x32_bf16(qf[m][1], kf[n][1], sac[m][n], 0, 0, 0);
                }

            // causal mask (only near diagonal)
            if (k0 + 63 > qmin){
                #pragma unroll
                for (int m = 0; m < 2; m++)
                    #pragma unroll
                    for (int n = 0; n < 4; n++)
                        #pragma unroll
                        for (int j = 0; j < 4; j++){
                            int qg = qmin + m*16 + g*4 + j;
                            int kg = k0 + n*16 + lr;
                            if (kg > qg) sac[m][n][j] = -1e30f;
                        }
            }

            // ---- online softmax (row stats reduced over the 16-lane k axis) ----
            #pragma unroll
            for (int m = 0; m < 2; m++){
                float fac[4];
                #pragma unroll
                for (int j = 0; j < 4; j++){
                    float tm = fmaxf(fmaxf(sac[m][0][j], sac[m][1][j]),
                                     fmaxf(sac[m][2][j], sac[m][3][j]));
                    tm = rmax16(tm);
                    float mnew = fmaxf(mrun[m][j], tm);
                    fac[j] = __expf(mrun[m][j] - mnew);
                    mrun[m][j] = mnew;
                    lrun[m][j] *= fac[j];
                }
                #pragma unroll
                for (int n = 0; n < 4; n++)
                    #pragma unroll
                    for (int j = 0; j < 4; j++)
                        oacc[m][n][j] *= fac[j];
                float ps[4] = {0.f, 0.f, 0.f, 0.f};
                #pragma unroll
                for (int n = 0; n < 4; n++)
                    #pragma unroll
                    for (int j = 0; j < 4; j++){
                        float p = __expf(sac[m][n][j] - mrun[m][j]);
                        ps[j] += p;
                        Pl[wq][(size_t)(m*16 + g*4 + j)*72 + n*16 + lr] = f2bf(p);
                    }
                #pragma unroll
                for (int j = 0; j < 4; j++)
                    lrun[m][j] += rsum16(ps[j]);
            }

            // ---- PV: O += P(32x64) @ V(64x64) ----
            bf16x8 pf[2][2], vf[4][2];
            #pragma unroll
            for (int m = 0; m < 2; m++)
                #pragma unroll
                for (int kk = 0; kk < 2; kk++)
                    pf[m][kk] = *(const bf16x8*)&Pl[wq][(size_t)(m*16 + lr)*72 + kk*32 + g*8];
            #pragma unroll
            for (int n = 0; n < 4; n++)
                #pragma unroll
                for (int kk = 0; kk < 2; kk++)
                    vf[n][kk] = *(const bf16x8*)&Vt[(size_t)(n*16 + lr)*72 + kk*32 + g*8];
            #pragma unroll
            for (int m = 0; m < 2; m++)
                #pragma unroll
                for (int n = 0; n < 4; n++){
                    oacc[m][n] = __builtin_amdgcn_mfma_f32_16x16x32_bf16(pf[m][0], vf[n][0], oacc[m][n], 0, 0, 0);
                    oacc[m][n] = __builtin_amdgcn_mfma_f32_16x16x32_bf16(pf[m][1], vf[n][1], oacc[m][n], 0, 0, 0);
                }
        }
        __syncthreads();
    }

    // ---- epilogue: O /= l, write merged ctx ----
    #pragma unroll
    for (int m = 0; m < 2; m++){
        #pragma unroll
        for (int j = 0; j < 4; j++){
            float inv = 1.0f / lrun[m][j];
            int q = q0 + wq*32 + m*16 + g*4 + j;
            u16* orow = ctx + (size_t)(b*S_ + q) * E_ + h*64;
            #pragma unroll
            for (int n = 0; n < 4; n++)
                orow[n*16 + lr] = f2bf(oacc[m][n][j] * inv);
        }
    }
}

// ---------------- launch ----------------
extern "C" void kernel_launch(void* const* d_in, const int* in_sizes, int n_in,
                              void* d_out, int out_size, void* d_ws, size_t ws_size,
                              hipStream_t stream){
    const float* x      = (const float*)d_in[0];
    const float* w_attn = (const float*)d_in[1];
    const float* b_attn = (const float*)d_in[2];
    const float* w_proj = (const float*)d_in[3];
    const float* b_proj = (const float*)d_in[4];
    float* out = (float*)d_out;

    char* ws = (char*)d_ws;
    u16* xb   = (u16*)(ws);                         //  8 MB  [4096][1024] bf16
    u16* waT  = (u16*)(ws + 8u*1024*1024);          //  6 MB  [3072][1024] bf16
    u16* wpT  = (u16*)(ws + 14u*1024*1024);         //  2 MB  [1024][1024] bf16
    u16* qkv  = (u16*)(ws + 16u*1024*1024);         // 24 MB  [4096][3072] bf16
    u16* ctxb = (u16*)(ws + 40u*1024*1024);         //  8 MB  [4096][1024] bf16

    cast_f32_bf16<<<(M_*E_/4 + 255)/256, 256, 0, stream>>>(x, xb, M_*E_/4);
    transpose_cast<<<dim3(N3/32, E_/32), dim3(32, 8), 0, stream>>>(w_attn, waT, E_, N3);
    transpose_cast<<<dim3(E_/32, E_/32), dim3(32, 8), 0, stream>>>(w_proj, wpT, E_, E_);
    gemm_bf16<true><<<(M_/128)*(N3/128), 256, 0, stream>>>(xb, waT, b_attn, qkv, M_, N3, E_);
    attn_mfma<<<B_*H_*(S_/128), 256, 0, stream>>>(qkv, ctxb);
    gemm_bf16<false><<<(M_/128)*(E_/128), 256, 0, stream>>>(ctxb, wpT, b_proj, out, M_, E_, E_);
}

// Round 3
// 181.699 us; speedup vs baseline: 24.7547x; 1.1786x over previous
//
#include <hip/hip_runtime.h>
#include <hip/hip_bf16.h>
#include <stdint.h>

#define B_ 2
#define S_ 2048
#define E_ 1024
#define H_ 16
#define D_ 64
#define M_ (B_*S_)      // 4096
#define N3 (3*E_)       // 3072

typedef unsigned short u16;
typedef float f32x4 __attribute__((ext_vector_type(4)));
typedef float f32x16 __attribute__((ext_vector_type(16)));
typedef __bf16 bf16x8 __attribute__((ext_vector_type(8)));
typedef u16 u16x8 __attribute__((ext_vector_type(8)));
typedef uint32_t u32x4 __attribute__((ext_vector_type(4)));

__device__ __forceinline__ u16 f2bf(float f){
    uint32_t u = __float_as_uint(f);
    u += 0x7fffu + ((u >> 16) & 1u);
    return (u16)(u >> 16);
}
__device__ __forceinline__ float bf2f(u16 v){ return __uint_as_float((uint32_t)v << 16); }

// ---------------- elementwise cast f32 -> bf16 (vectorized) ----------------
__global__ __launch_bounds__(256) void cast_f32_bf16(const float* __restrict__ in,
                                                     u16* __restrict__ out, int n4){
    int i = blockIdx.x * 256 + threadIdx.x;
    if (i < n4){
        float4 v = ((const float4*)in)[i];
        uint2 p;
        p.x = (uint32_t)f2bf(v.x) | ((uint32_t)f2bf(v.y) << 16);
        p.y = (uint32_t)f2bf(v.z) | ((uint32_t)f2bf(v.w) << 16);
        ((uint2*)out)[i] = p;
    }
}

// ---------------- tiled transpose + cast: in[R][C] f32 -> out[C][R] bf16 ----------------
__global__ __launch_bounds__(256) void transpose_cast(const float* __restrict__ in,
                                                      u16* __restrict__ out, int R, int C){
    __shared__ float t[32][33];
    int bx = blockIdx.x, by = blockIdx.y;
    int tx = threadIdx.x, ty = threadIdx.y;
    int x = bx * 32 + tx;
    #pragma unroll
    for (int i = 0; i < 4; i++)
        t[ty + 8*i][tx] = in[(size_t)(by*32 + ty + 8*i) * C + x];
    __syncthreads();
    #pragma unroll
    for (int i = 0; i < 4; i++)
        out[(size_t)(bx*32 + ty + 8*i) * R + by*32 + tx] = f2bf(t[tx][ty + 8*i]);
}

// ---------------- bf16 MFMA GEMM: C[M][N] = A[M][K] * BT[N][K]^T + bias ----------------
template<bool OUT_BF16>
__global__ __launch_bounds__(256) void gemm_bf16(const u16* __restrict__ A,
                                                 const u16* __restrict__ BT,
                                                 const float* __restrict__ bias,
                                                 void* __restrict__ Cout,
                                                 int M, int N, int K){
    __shared__ u16 Al[128 * 64];
    __shared__ u16 Bl[128 * 64];
    int nb = N >> 7;
    int bm = blockIdx.x / nb, bn = blockIdx.x % nb;
    int row0 = bm << 7, col0 = bn << 7;
    int tid  = threadIdx.x;
    int wave = tid >> 6, lane = tid & 63;
    int wm = wave >> 1, wn = wave & 1;
    int lr = lane & 15, lk = (lane >> 4) << 3;
    int trow = tid >> 3, tcol = (tid & 7) << 3;

    f32x4 acc[4][4] = {};

    for (int k0 = 0; k0 < K; k0 += 64){
        #pragma unroll
        for (int i = 0; i < 4; i++){
            const u16* ga = A + (size_t)(row0 + i*32 + trow) * K + k0 + tcol;
            __builtin_amdgcn_global_load_lds(
                (const __attribute__((address_space(1))) void*)ga,
                (__attribute__((address_space(3))) void*)&Al[i*2048 + wave*512],
                16, 0, 0);
        }
        #pragma unroll
        for (int i = 0; i < 4; i++){
            const u16* gb = BT + (size_t)(col0 + i*32 + trow) * K + k0 + tcol;
            __builtin_amdgcn_global_load_lds(
                (const __attribute__((address_space(1))) void*)gb,
                (__attribute__((address_space(3))) void*)&Bl[i*2048 + wave*512],
                16, 0, 0);
        }
        __syncthreads();

        #pragma unroll
        for (int ks = 0; ks < 2; ks++){
            bf16x8 af[4], bfr[4];
            #pragma unroll
            for (int m = 0; m < 4; m++)
                af[m] = *(const bf16x8*)&Al[(wm*64 + m*16 + lr) * 64 + ks*32 + lk];
            #pragma unroll
            for (int n = 0; n < 4; n++)
                bfr[n] = *(const bf16x8*)&Bl[(wn*64 + n*16 + lr) * 64 + ks*32 + lk];
            #pragma unroll
            for (int m = 0; m < 4; m++)
                #pragma unroll
                for (int n = 0; n < 4; n++)
                    acc[m][n] = __builtin_amdgcn_mfma_f32_16x16x32_bf16(af[m], bfr[n], acc[m][n], 0, 0, 0);
        }
        __syncthreads();
    }

    #pragma unroll
    for (int m = 0; m < 4; m++){
        int gr = row0 + wm*64 + m*16 + ((lane >> 4) << 2);
        #pragma unroll
        for (int n = 0; n < 4; n++){
            int gc = col0 + wn*64 + n*16 + lr;
            float bv = bias[gc];
            #pragma unroll
            for (int j = 0; j < 4; j++){
                float v = acc[m][n][j] + bv;
                if (OUT_BF16) ((u16*)Cout)[(size_t)(gr + j) * N + gc] = f2bf(v);
                else          ((float*)Cout)[(size_t)(gr + j) * N + gc] = v;
            }
        }
    }
}

// ---------------- MFMA causal flash attention, swapped-operand 32x32 ----------------
// S^T = mfma(K, Q): col = lane&31 = q, row = (r&3)+8*(r>>2)+4*hi = k  -> P row lane-local.
// O^T = mfma(V^T, P): col = q -> rescale per-lane uniform.
__global__ __launch_bounds__(256) void attn_mfma2(const u16* __restrict__ qkv,
                                                  u16* __restrict__ ctx){
    __shared__ u16 Kl[2][64*64];   // K rows [k][d], XOR-swizzled chunks (key = (k>>2)&7)
    __shared__ u16 Vt[2][64*64];   // V^T rows [d][k], XOR-swizzled (key = (d>>2)&7)
    __shared__ u16 Ol[4][32*72];   // per-wave O transpose scratch

    int t  = blockIdx.x;
    int raw = t & 15;
    int qb = (raw & 1) ? (15 - (raw >> 1)) : (raw >> 1);  // balance causal work
    int h  = (t >> 4) & 15;
    int b  = t >> 8;
    int q0 = qb * 128;

    int tid  = threadIdx.x;
    int wq   = tid >> 6, lane = tid & 63;
    int l31  = lane & 31, hi = lane >> 5;

    const u16* base = qkv + (size_t)b * S_ * N3;
    int qmin = q0 + wq*32;
    int qg   = qmin + l31;            // this lane's q row

    // Q B-frag: lane holds col q, d-slice = 16s + 8*hi + e; pre-scale 0.125*log2(e)
    const float QSC = 0.17328679513998633f;
    bf16x8 qf[4];
    #pragma unroll
    for (int s = 0; s < 4; s++){
        u16x8 v = *(const u16x8*)(base + (size_t)qg * N3 + h*64 + 16*s + 8*hi);
        u16x8 r;
        #pragma unroll
        for (int i = 0; i < 8; i++) r[i] = f2bf(bf2f(v[i]) * QSC);
        qf[s] = __builtin_bit_cast(bf16x8, r);
    }

    f32x16 oacc[2] = {};
    float mrow = -5000.f, lrow = 0.f;
    const float MASKV = -30000.f;

    int rp = tid >> 3, ch = tid & 7;  // V staging assignment
    u16x8 va, vb;                     // V tile held in regs (async-split)
    int nkt = q0/64 + 2;

    // ---- prologue: stage tile 0 ----
    {
        #pragma unroll
        for (int c = 0; c < 2; c++){
            int row = c*32 + wq*8 + (lane >> 3);
            int chg = (lane & 7) ^ ((row >> 2) & 7);
            const u16* g = base + (size_t)row * N3 + E_ + h*64 + chg*8;
            __builtin_amdgcn_global_load_lds(
                (const __attribute__((address_space(1))) void*)g,
                (__attribute__((address_space(3))) void*)&Kl[0][c*2048 + wq*512], 16, 0, 0);
        }
        va = *(const u16x8*)(base + (size_t)(2*rp)   * N3 + 2*E_ + h*64 + ch*8);
        vb = *(const u16x8*)(base + (size_t)(2*rp+1) * N3 + 2*E_ + h*64 + ch*8);
        #pragma unroll
        for (int e = 0; e < 8; e++){
            int d = ch*8 + e;
            uint32_t pkv = (uint32_t)va[e] | ((uint32_t)vb[e] << 16);
            *(uint32_t*)((char*)&Vt[0][0] + d*128 + (((rp>>2) ^ ((d>>2)&7)) << 4) + (rp&3)*4) = pkv;
        }
    }
    __syncthreads();

    for (int kt = 0; kt < nkt; kt++){
        int cur = kt & 1, nxt = cur ^ 1;
        int k0  = kt * 64;
        bool pre = (kt + 1 < nkt);

        if (pre){
            int kn = k0 + 64;
            #pragma unroll
            for (int c = 0; c < 2; c++){
                int row = c*32 + wq*8 + (lane >> 3);
                int chg = (lane & 7) ^ ((row >> 2) & 7);
                const u16* g = base + (size_t)(kn + row) * N3 + E_ + h*64 + chg*8;
                __builtin_amdgcn_global_load_lds(
                    (const __attribute__((address_space(1))) void*)g,
                    (__attribute__((address_space(3))) void*)&Kl[nxt][c*2048 + wq*512], 16, 0, 0);
            }
            va = *(const u16x8*)(base + (size_t)(kn + 2*rp)   * N3 + 2*E_ + h*64 + ch*8);
            vb = *(const u16x8*)(base + (size_t)(kn + 2*rp+1) * N3 + 2*E_ + h*64 + ch*8);
        }

        if (k0 <= qmin + 31){
            // ---- QK^T (swapped): sac[sub] = S^T[64k x 32q] ----
            f32x16 sac[2] = {};
            #pragma unroll
            for (int sub = 0; sub < 2; sub++){
                int row = sub*32 + l31;
                int key = (row >> 2) & 7;
                #pragma unroll
                for (int s = 0; s < 4; s++){
                    bf16x8 kf = *(const bf16x8*)((const char*)&Kl[cur][0]
                                 + row*128 + (((2*s + hi) ^ key) << 4));
                    sac[sub] = __builtin_amdgcn_mfma_f32_32x32x16_bf16(kf, qf[s], sac[sub], 0, 0, 0);
                }
            }
            // causal mask
            if (k0 + 63 > qmin){
                #pragma unroll
                for (int sub = 0; sub < 2; sub++)
                    #pragma unroll
                    for (int r = 0; r < 16; r++){
                        int kg = k0 + sub*32 + (r&3) + 8*(r>>2) + 4*hi;
                        if (kg > qg) sac[sub][r] = MASKV;
                    }
            }
            // ---- row max (in-register tree + cross-half shfl) ----
            float mt[16];
            #pragma unroll
            for (int i = 0; i < 16; i++) mt[i] = fmaxf(sac[0][i], sac[1][i]);
            #pragma unroll
            for (int st = 8; st >= 1; st >>= 1)
                #pragma unroll
                for (int i = 0; i < st; i++) mt[i] = fmaxf(mt[i], mt[i+st]);
            float tmax = fmaxf(mt[0], __shfl_xor(mt[0], 32));
            // ---- defer-max rescale (THR = 8 in log2 domain) ----
            if (tmax > mrow + 8.f){
                float fac = exp2f(mrow - tmax);
                mrow = tmax;
                lrow *= fac;
                oacc[0] *= fac;
                oacc[1] *= fac;
            }
            // ---- P = exp2(S - m), per-lane partial l-sum ----
            float p[32];
            #pragma unroll
            for (int sub = 0; sub < 2; sub++)
                #pragma unroll
                for (int r = 0; r < 16; r++)
                    p[sub*16 + r] = exp2f(sac[sub][r] - mrow);
            float ss[16];
            #pragma unroll
            for (int i = 0; i < 16; i++) ss[i] = p[i] + p[16+i];
            #pragma unroll
            for (int st = 8; st >= 1; st >>= 1)
                #pragma unroll
                for (int i = 0; i < st; i++) ss[i] += ss[i+st];
            lrow += ss[0];
            // ---- pack P to bf16 pairs, swap halves (T12) ----
            uint32_t pk[16], sw[16];
            #pragma unroll
            for (int i = 0; i < 16; i++){
                uint32_t r;
                asm("v_cvt_pk_bf16_f32 %0, %1, %2" : "=v"(r) : "v"(p[2*i]), "v"(p[2*i+1]));
                pk[i] = r;
            }
            #pragma unroll
            for (int i = 0; i < 16; i++) sw[i] = (uint32_t)__shfl_xor((int)pk[i], 32);
            // ---- PV (swapped): oacc[dt] += mfma(V^T frag, P frag) ----
            #pragma unroll
            for (int dt = 0; dt < 2; dt++){
                int d = dt*32 + l31;
                int key = (d >> 2) & 7;
                #pragma unroll
                for (int s = 0; s < 4; s++){
                    bf16x8 vf = *(const bf16x8*)((const char*)&Vt[cur][0]
                                 + d*128 + (((2*s + hi) ^ key) << 4));
                    u32x4 pw;
                    pw[0] = hi ? sw[4*s+2] : pk[4*s+0];
                    pw[1] = hi ? sw[4*s+3] : pk[4*s+1];
                    pw[2] = hi ? pk[4*s+2] : sw[4*s+0];
                    pw[3] = hi ? pk[4*s+3] : sw[4*s+1];
                    bf16x8 pfr = __builtin_bit_cast(bf16x8, pw);
                    oacc[dt] = __builtin_amdgcn_mfma_f32_32x32x16_bf16(vf, pfr, oacc[dt], 0, 0, 0);
                }
            }
        }

        if (pre){
            #pragma unroll
            for (int e = 0; e < 8; e++){
                int d = ch*8 + e;
                uint32_t pkv = (uint32_t)va[e] | ((uint32_t)vb[e] << 16);
                *(uint32_t*)((char*)&Vt[nxt][0] + d*128 + (((rp>>2) ^ ((d>>2)&7)) << 4) + (rp&3)*4) = pkv;
            }
        }
        __syncthreads();
    }

    // ---- epilogue: combine halves, normalize, transpose via LDS, coalesced store ----
    lrow += __shfl_xor(lrow, 32);
    float inv = 1.0f / lrow;
    #pragma unroll
    for (int dt = 0; dt < 2; dt++)
        #pragma unroll
        for (int r = 0; r < 16; r++){
            int d = dt*32 + (r&3) + 8*(r>>2) + 4*hi;
            Ol[wq][l31*72 + d] = f2bf(oacc[dt][r] * inv);
        }
    __syncthreads();
    {
        int q = lane >> 1, half = lane & 1;
        const u16* src = &Ol[wq][q*72 + half*32];
        u16* dst = ctx + (size_t)(b*S_ + q0 + wq*32 + q) * E_ + h*64 + half*32;
        #pragma unroll
        for (int i = 0; i < 4; i++)
            *(u16x8*)(dst + i*8) = *(const u16x8*)(src + i*8);
    }
}

// ---------------- launch ----------------
extern "C" void kernel_launch(void* const* d_in, const int* in_sizes, int n_in,
                              void* d_out, int out_size, void* d_ws, size_t ws_size,
                              hipStream_t stream){
    const float* x      = (const float*)d_in[0];
    const float* w_attn = (const float*)d_in[1];
    const float* b_attn = (const float*)d_in[2];
    const float* w_proj = (const float*)d_in[3];
    const float* b_proj = (const float*)d_in[4];
    float* out = (float*)d_out;

    char* ws = (char*)d_ws;
    u16* xb   = (u16*)(ws);                         //  8 MB  [4096][1024] bf16
    u16* waT  = (u16*)(ws + 8u*1024*1024);          //  6 MB  [3072][1024] bf16
    u16* wpT  = (u16*)(ws + 14u*1024*1024);         //  2 MB  [1024][1024] bf16
    u16* qkv  = (u16*)(ws + 16u*1024*1024);         // 24 MB  [4096][3072] bf16
    u16* ctxb = (u16*)(ws + 40u*1024*1024);         //  8 MB  [4096][1024] bf16

    cast_f32_bf16<<<(M_*E_/4 + 255)/256, 256, 0, stream>>>(x, xb, M_*E_/4);
    transpose_cast<<<dim3(N3/32, E_/32), dim3(32, 8), 0, stream>>>(w_attn, waT, E_, N3);
    transpose_cast<<<dim3(E_/32, E_/32), dim3(32, 8), 0, stream>>>(w_proj, wpT, E_, E_);
    gemm_bf16<true><<<(M_/128)*(N3/128), 256, 0, stream>>>(xb, waT, b_attn, qkv, M_, N3, E_);
    attn_mfma2<<<B_*H_*(S_/128), 256, 0, stream>>>(qkv, ctxb);
    gemm_bf16<false><<<(M_/128)*(E_/128), 256, 0, stream>>>(ctxb, wpT, b_proj, out, M_, E_, E_);
}